// Round 3
// baseline (6016.195 us; speedup 1.0000x reference)
//
#include <hip/hip_runtime.h>

typedef _Float16 f16;
typedef f16 f16x4 __attribute__((ext_vector_type(4)));
typedef f16 f16x8 __attribute__((ext_vector_type(8)));
typedef float f32x4 __attribute__((ext_vector_type(4)));
typedef unsigned int u32;

#define MFMA __builtin_amdgcn_mfma_f32_16x16x32_f16

constexpr int Bsz = 256, T = 512, D = 128, H = 512, C = 128;
constexpr int ROWS = 16;          // batch rows per block (MFMA M)
constexpr int TPB  = 512;         // 8 waves
constexpr int NBT  = Bsz / ROWS;  // 16 batch tiles
constexpr int NCG  = 4;           // column groups (H split across blocks)
constexpr int HC   = H / NCG;     // 128 h-cols per block
constexpr int LDH  = H + 8;       // LDS pad
constexpr int LDX  = D + 8;
constexpr int NTH  = H / 16;      // 32 n-tiles over H
constexpr int KTH  = H / 32;      // 16 k-tiles over H
constexpr int KTX  = D / 32;      // 4 k-tiles over D

// Pack fp32 [K][N] row-major -> fp16 MFMA-fragment order (verified).
__global__ void pack_w(const float* __restrict__ W, int K, int N, f16* __restrict__ out) {
    int total = K * N;
    int NT = N / 16;
    for (int idx = blockIdx.x * blockDim.x + threadIdx.x; idx < total;
         idx += gridDim.x * blockDim.x) {
        int e    = idx & 7;
        int lane = (idx >> 3) & 63;
        int tile = idx >> 9;
        int kt = tile / NT, nt = tile % NT;
        int k = kt * 32 + 4 * (lane >> 4) + (e & 3) + 16 * (e >> 2);
        int n = nt * 16 + (lane & 15);
        out[idx] = (f16)W[(size_t)k * N + n];
    }
}

__global__ void zero_flags(u32* __restrict__ f) { f[threadIdx.x] = 0u; }

__device__ __forceinline__ f16x8 load_a(const f16* base, int ld, int kt, int l15, int l4) {
    const f16* p = base + l15 * ld + kt * 32 + 4 * l4;
    f16x4 lo = *(const f16x4*)p;
    f16x4 hi = *(const f16x4*)(p + 16);
    f16x8 r = {lo[0], lo[1], lo[2], lo[3], hi[0], hi[1], hi[2], hi[3]};
    return r;
}

__device__ __forceinline__ float fast_tanh(float v) {
    v = fminf(fmaxf(v, -8.f), 8.f);
    float e = __expf(2.f * v);
    return __fdividef(e - 1.f, e + 1.f);
}

// grid = 64: blockIdx = cg*16 + bt  (keeps a btile's 4 blocks on one XCD
// under round-robin dispatch — perf heuristic only, not correctness).
// Each block: batch rows [bt*16,+16), h-cols [cg*128,+128). Whh/Whx strips
// fully register-pinned; per-step cross-block h exchange via global flags.
__global__ __launch_bounds__(TPB, 2) void rnn_main(
    const float* __restrict__ x, const f16* __restrict__ wpack,
    const float* __restrict__ bh, const float* __restrict__ bp,
    f16* __restrict__ hx, u32* __restrict__ flags, float* __restrict__ out) {
    const f16* Whx_p = wpack;
    const f16* Whh_p = wpack + D * H;
    const f16* Wph_p = wpack + D * H + H * H;

    __shared__ f16 hbuf[2][ROWS][LDH];   // full 512-col h state
    __shared__ f16 xbuf[2][ROWS][LDX];

    const int tid = threadIdx.x, lane = tid & 63, w = tid >> 6;
    const int l15 = lane & 15, l4 = lane >> 4;
    const int bt = blockIdx.x & 15, cg = blockIdx.x >> 4;
    const int b0 = bt * ROWS;
    const int ntg = cg * (HC / 16) + w;  // this wave's global n-tile (0..31)
    const int xrow = tid >> 5, xd0 = (tid & 31) * 4;

    // ---- pin weights in registers (zero streaming in the loop) ----
    f16x8 wh[KTH];  // Whh strip for n-tile ntg: 64 VGPRs
#pragma unroll
    for (int kt = 0; kt < KTH; kt++)
        wh[kt] = *(const f16x8*)(Whh_p + (((size_t)kt * NTH + ntg) * 64 + lane) * 8);
    f16x8 wx[KTX];  // Whx strip: 16 VGPRs
#pragma unroll
    for (int kt = 0; kt < KTX; kt++)
        wx[kt] = *(const f16x8*)(Whx_p + (((size_t)kt * NTH + ntg) * 64 + lane) * 8);
    const float bhv = bh[ntg * 16 + l15];

    // h0 = 0; stage x[t=0]
    for (int i = tid; i < ROWS * LDH; i += TPB) (&hbuf[0][0][0])[i] = (f16)0.f;
    {
        float4 v = *(const float4*)&x[((size_t)(b0 + xrow) * T + 0) * D + xd0];
        f16x4 h4 = {(f16)v.x, (f16)v.y, (f16)v.z, (f16)v.w};
        *(f16x4*)&xbuf[0][xrow][xd0] = h4;
    }
    __syncthreads();

    // exchange addressing: hx[parity][bt][cg][row16][col128] f16
    const int erow = tid >> 5, ec = (tid & 31) * 4;
    u32* myflag = flags + bt * 16 + cg;
    const int pcg[3] = {(cg + 1) & 3, (cg + 2) & 3, (cg + 3) & 3};

    int p = 0;
    for (int t = 0; t < T; t++) {
        // prefetch x_{t+1}
        float4 xv;
        const bool havex = (t + 1 < T);
        if (havex)
            xv = *(const float4*)&x[((size_t)(b0 + xrow) * T + (t + 1)) * D + xd0];

        // 4 independent accumulator chains (hide dependent-MFMA latency)
        f32x4 a0 = {bhv, bhv, bhv, bhv}, a1 = {0.f, 0.f, 0.f, 0.f};
        f32x4 a2 = {0.f, 0.f, 0.f, 0.f}, a3 = {0.f, 0.f, 0.f, 0.f};
        const f16* hb = &hbuf[p][0][0];
        const f16* xb = &xbuf[p][0][0];
#pragma unroll
        for (int kt = 0; kt < KTX; kt++)
            a0 = MFMA(load_a(xb, LDX, kt, l15, l4), wx[kt], a0, 0, 0, 0);
#pragma unroll
        for (int kt = 0; kt < 6; kt++)
            a1 = MFMA(load_a(hb, LDH, kt, l15, l4), wh[kt], a1, 0, 0, 0);
#pragma unroll
        for (int kt = 6; kt < 11; kt++)
            a2 = MFMA(load_a(hb, LDH, kt, l15, l4), wh[kt], a2, 0, 0, 0);
#pragma unroll
        for (int kt = 11; kt < 16; kt++)
            a3 = MFMA(load_a(hb, LDH, kt, l15, l4), wh[kt], a3, 0, 0, 0);
        f32x4 acc = (a0 + a1) + (a2 + a3);

        // h_new own n-tile -> LDS (C/D layout: col=lane&15, row=4*(lane>>4)+r)
#pragma unroll
        for (int r = 0; r < 4; r++) {
            float th = fast_tanh(acc[r]);
            hbuf[p ^ 1][l4 * 4 + r][ntg * 16 + l15] = (f16)th;
        }
        if (havex) {
            f16x4 h4 = {(f16)xv.x, (f16)xv.y, (f16)xv.z, (f16)xv.w};
            *(f16x4*)&xbuf[p ^ 1][xrow][xd0] = h4;
        }
        __syncthreads();  // own chunk complete in LDS

        // publish own 4KB chunk (coalesced f16x4), release
        const int par = (t + 1) & 1;
        {
            f16x4 v = *(const f16x4*)&hbuf[p ^ 1][erow][cg * HC + ec];
            f16* dst = hx + ((((size_t)par * NBT + bt) * NCG + cg) * ROWS + erow) * HC + ec;
            *(f16x4*)dst = v;
        }
        __threadfence();   // agent-scope release: drain + make visible
        __syncthreads();   // all waves' fences done before flag
        if (tid == 0)
            __hip_atomic_store(myflag, (u32)(t + 1), __ATOMIC_RELAXED,
                               __HIP_MEMORY_SCOPE_AGENT);
        if (tid >= 1 && tid <= 3) {
            u32* pf = flags + bt * 16 + pcg[tid - 1];
            while (__hip_atomic_load(pf, __ATOMIC_RELAXED, __HIP_MEMORY_SCOPE_AGENT) <
                   (u32)(t + 1)) {
            }
            __threadfence();  // acquire: invalidate CU L1 / XCD L2
        }
        __syncthreads();  // peers' h_{t+1} now visible

        // gather 3 peer chunks -> LDS
        {
            const f16* src0 =
                hx + ((((size_t)par * NBT + bt) * NCG + pcg[0]) * ROWS + erow) * HC + ec;
            const f16* src1 =
                hx + ((((size_t)par * NBT + bt) * NCG + pcg[1]) * ROWS + erow) * HC + ec;
            const f16* src2 =
                hx + ((((size_t)par * NBT + bt) * NCG + pcg[2]) * ROWS + erow) * HC + ec;
            f16x4 v0 = *(const f16x4*)src0;
            f16x4 v1 = *(const f16x4*)src1;
            f16x4 v2 = *(const f16x4*)src2;
            *(f16x4*)&hbuf[p ^ 1][erow][pcg[0] * HC + ec] = v0;
            *(f16x4*)&hbuf[p ^ 1][erow][pcg[1] * HC + ec] = v1;
            *(f16x4*)&hbuf[p ^ 1][erow][pcg[2] * HC + ec] = v2;
        }
        __syncthreads();
        p ^= 1;
    }

    // out = h_T @ Wph + bp ; block (bt,cg) owns out cols [cg*32, cg*32+32)
    if (w < 2) {
        const int nt = cg * 2 + w;  // Wph n-tile (C/16 = 8 total)
        float bpv = bp[nt * 16 + l15];
        f32x4 acc = {bpv, bpv, bpv, bpv};
#pragma unroll 4
        for (int kt = 0; kt < KTH; kt++) {
            f16x8 a = load_a(&hbuf[p][0][0], LDH, kt, l15, l4);
            f16x8 b = *(const f16x8*)(Wph_p + (((size_t)kt * (C / 16) + nt) * 64 + lane) * 8);
            acc = MFMA(a, b, acc, 0, 0, 0);
        }
#pragma unroll
        for (int r = 0; r < 4; r++)
            out[(size_t)(b0 + l4 * 4 + r) * C + nt * 16 + l15] = acc[r];
    }
}

extern "C" void kernel_launch(void* const* d_in, const int* in_sizes, int n_in,
                              void* d_out, int out_size, void* d_ws, size_t ws_size,
                              hipStream_t stream) {
    const float* x   = (const float*)d_in[0];
    const float* Whx = (const float*)d_in[1];
    const float* Whh = (const float*)d_in[2];
    const float* Wph = (const float*)d_in[3];
    const float* bh  = (const float*)d_in[4];
    const float* bp  = (const float*)d_in[5];

    // workspace: [packed f16 weights 768KB][hx exchange 512KB][flags 1KB]
    f16* wp = (f16*)d_ws;
    const size_t wel = (size_t)D * H + (size_t)H * H + (size_t)H * C;
    f16* hx = wp + wel;
    u32* flags = (u32*)(hx + (size_t)2 * NBT * NCG * ROWS * HC);

    pack_w<<<dim3(128), 256, 0, stream>>>(Whx, D, H, wp);
    pack_w<<<dim3(512), 256, 0, stream>>>(Whh, H, H, wp + D * H);
    pack_w<<<dim3(128), 256, 0, stream>>>(Wph, H, C, wp + D * H + H * H);
    zero_flags<<<dim3(1), 256, 0, stream>>>(flags);  // must precede rnn_main (replay-safe)

    rnn_main<<<dim3(NBT * NCG), TPB, 0, stream>>>(x, wp, bh, bp, hx, flags,
                                                  (float*)d_out);
}

// Round 4
// 1652.391 us; speedup vs baseline: 3.6409x; 3.6409x over previous
//
#include <hip/hip_runtime.h>
#include <type_traits>

typedef _Float16 f16;
typedef f16 f16x4 __attribute__((ext_vector_type(4)));
typedef f16 f16x8 __attribute__((ext_vector_type(8)));
typedef float f32x4 __attribute__((ext_vector_type(4)));
typedef unsigned int u32;

#define MFMA __builtin_amdgcn_mfma_f32_16x16x32_f16

constexpr int Bsz = 256, T = 512, D = 128, H = 512, C = 128;
constexpr int ROWS = 16;          // batch rows per block (MFMA M)
constexpr int TPB  = 512;         // 8 waves
constexpr int LDH  = H + 8;       // stride 520 f16 = 260 dwords ≡ 4 mod 32: b128 bank-uniform
constexpr int LDX  = D + 8;
constexpr int NTG  = H / 16;      // 32 n-tiles over H
constexpr int PKT  = 8;           // Whh k-tiles pinned in regs (kt 0..7)
constexpr int KTL  = 3;           // Whh k-tiles in LDS (kt 8..10); kt 11..15 streamed
constexpr size_t XSTRIDE = (size_t)16 * NTG * 256;  // xproj elems per timestep

// Pack fp32 [K][N] row-major -> fp16 MFMA-fragment order.
// k-slot map (BIJECTION, must match A-side load_a): k = kt*32 + 8*(lane>>4) + e.
// Contiguous in e so the A-side fragment is a single 16B LDS read.
__global__ void pack_w(const float* __restrict__ W, int K, int N, f16* __restrict__ out) {
    int total = K * N;
    int NT = N / 16;
    for (int idx = blockIdx.x * blockDim.x + threadIdx.x; idx < total;
         idx += gridDim.x * blockDim.x) {
        int e    = idx & 7;
        int lane = (idx >> 3) & 63;
        int tile = idx >> 9;
        int kt = tile / NT, nt = tile % NT;
        int k = kt * 32 + 8 * (lane >> 4) + e;   // contiguous k-map
        int n = nt * 16 + (lane & 15);
        out[idx] = (f16)W[(size_t)k * N + n];
    }
}

// A-fragment: row = lane&15, k = kt*32 + 8*(lane>>4) + {0..7} -> one b128 read.
__device__ __forceinline__ f16x8 load_a(const f16* base, int ld, int kt, int l15, int l4) {
    return *(const f16x8*)(base + l15 * ld + kt * 32 + 8 * l4);
}

// tanh(v) = 1 - 2/(e^{2v}+1); no clamp needed (exp->inf => rcp->0 => +/-1).
__device__ __forceinline__ float fast_tanh(float v) {
    float e = __expf(2.f * v);
    return 1.f - __fdividef(2.f, e + 1.f);
}

// xproj = x_t @ Whx + bh in MFMA C-fragment order (f32 or f16). Runs on all CUs.
template <typename OT>
__global__ __launch_bounds__(TPB, 2) void xproj_k(
    const float* __restrict__ x, const f16* __restrict__ wpack,
    const float* __restrict__ bh, OT* __restrict__ xp) {
    const f16* Whx_p = wpack;
    __shared__ __align__(16) f16 xb[2][ROWS][LDX];
    const int tid = threadIdx.x, lane = tid & 63, w = tid >> 6;
    const int l15 = lane & 15, l4 = lane >> 4;
    const int bt = blockIdx.x;       // 0..15
    const int t0 = blockIdx.y * 16;  // chunks of 16 timesteps
    const int b0 = bt * ROWS;
    const int xrow = tid >> 5, xd0 = (tid & 31) * 4;
    const int ntg0 = w * 4;

    float bh4[4];
#pragma unroll
    for (int nt = 0; nt < 4; nt++) bh4[nt] = bh[(ntg0 + nt) * 16 + l15];
    {
        float4 v = *(const float4*)&x[((size_t)(b0 + xrow) * T + t0) * D + xd0];
        f16x4 h4 = {(f16)v.x, (f16)v.y, (f16)v.z, (f16)v.w};
        *(f16x4*)&xb[0][xrow][xd0] = h4;
    }
    __syncthreads();

    int p = 0;
    for (int tt = 0; tt < 16; tt++) {
        int t = t0 + tt;
        float4 xv;
        const bool havex = (tt + 1 < 16);
        if (havex)
            xv = *(const float4*)&x[((size_t)(b0 + xrow) * T + (t + 1)) * D + xd0];
        f32x4 acc[4];
#pragma unroll
        for (int nt = 0; nt < 4; nt++)
            acc[nt] = (f32x4){bh4[nt], bh4[nt], bh4[nt], bh4[nt]};
#pragma unroll
        for (int kt = 0; kt < D / 32; kt++) {
            f16x8 a = load_a(&xb[p][0][0], LDX, kt, l15, l4);
            const f16* btp = Whx_p + (((size_t)kt * NTG + ntg0) * 64 + lane) * 8;
#pragma unroll
            for (int nt = 0; nt < 4; nt++) {
                f16x8 b = *(const f16x8*)(btp + (size_t)nt * 512);
                acc[nt] = MFMA(a, b, acc[nt], 0, 0, 0);
            }
        }
        if (havex) {
            f16x4 h4 = {(f16)xv.x, (f16)xv.y, (f16)xv.z, (f16)xv.w};
            *(f16x4*)&xb[p ^ 1][xrow][xd0] = h4;
        }
        OT* op = xp + (((size_t)t * 16 + bt) * NTG + ntg0) * 256 + (size_t)lane * 4;
#pragma unroll
        for (int nt = 0; nt < 4; nt++) {
            if constexpr (std::is_same_v<OT, float>) {
                *(f32x4*)(op + (size_t)nt * 256) = acc[nt];
            } else {
                f16x4 v = {(f16)acc[nt][0], (f16)acc[nt][1], (f16)acc[nt][2],
                           (f16)acc[nt][3]};
                *(f16x4*)(op + (size_t)nt * 256) = v;
            }
        }
        __syncthreads();
        p ^= 1;
    }
}

// XP=1: f32 xproj. XP=2: f16 xproj. XP=0: in-loop Whx fallback.
template <int XP>
__global__ __launch_bounds__(TPB, 2) void rnn_main(
    const float* __restrict__ x, const f16* __restrict__ wpack,
    const void* __restrict__ xproj, const float* __restrict__ bh,
    const float* __restrict__ bp, float* __restrict__ out) {
    const f16* Whx_p = wpack;
    const f16* Whh_p = wpack + D * H;
    const f16* Wph_p = wpack + D * H + H * H;

    __shared__ __align__(16) f16 hbuf[2][ROWS][LDH];           // 33.3 KB
    __shared__ __align__(16) f16 whh_lds[KTL * NTG * 64 * 8];  // 96 KB, kt 8..10
    __shared__ __align__(16) f16 xbuf[(XP == 0) ? 2 : 1][(XP == 0) ? ROWS : 1]
                                     [(XP == 0) ? LDX : 8];

    const int tid = threadIdx.x, lane = tid & 63, w = tid >> 6;
    const int l15 = lane & 15, l4 = lane >> 4;
    const int b0 = blockIdx.x * ROWS;
    const int xrow = tid >> 5, xd0 = (tid & 31) * 4;
    const int ntg0 = w * 4;

    // Pinned Whh kt 0..7 (128 regs, AGPR-resident; at the 2-wave/SIMD ceiling).
    f16x8 wreg[PKT][4];
#pragma unroll
    for (int kt = 0; kt < PKT; kt++)
#pragma unroll
        for (int nt = 0; nt < 4; nt++)
            wreg[kt][nt] =
                *(const f16x8*)(Whh_p + (((size_t)kt * NTG + ntg0 + nt) * 64 + lane) * 8);

    // Stage Whh kt 8..10 into LDS.
    {
        const f16* src = Whh_p + (size_t)PKT * NTG * 512;
        for (int i = tid; i < KTL * NTG * 64; i += TPB)
            *(f16x8*)&whh_lds[(size_t)i * 8] = *(const f16x8*)(src + (size_t)i * 8);
    }
    for (int i = tid; i < ROWS * LDH; i += TPB) (&hbuf[0][0][0])[i] = (f16)0.f;

    float bh4[4];
    const float* xpf = nullptr;
    const f16* xph = nullptr;
    if constexpr (XP == 1) {
        xpf = (const float*)xproj + (((size_t)blockIdx.x * NTG + ntg0) * 64 + lane) * 4;
    } else if constexpr (XP == 2) {
        xph = (const f16*)xproj + (((size_t)blockIdx.x * NTG + ntg0) * 64 + lane) * 4;
    } else {
#pragma unroll
        for (int nt = 0; nt < 4; nt++) bh4[nt] = bh[(ntg0 + nt) * 16 + l15];
        float4 v = *(const float4*)&x[((size_t)(b0 + xrow) * T + 0) * D + xd0];
        f16x4 h4 = {(f16)v.x, (f16)v.y, (f16)v.z, (f16)v.w};
        *(f16x4*)&xbuf[0][xrow][xd0] = h4;
    }

    // Prologue: preload streamed kt 11 -> sA, kt 12 -> sB.
    f16x8 sA[4], sB[4];
    {
        const f16* wb0 = Whh_p + ((size_t)ntg0 * 64 + lane) * 8;
#pragma unroll
        for (int nt = 0; nt < 4; nt++)
            sA[nt] = *(const f16x8*)(wb0 + ((size_t)11 * NTG + nt) * 512);
#pragma unroll
        for (int nt = 0; nt < 4; nt++)
            sB[nt] = *(const f16x8*)(wb0 + ((size_t)12 * NTG + nt) * 512);
    }
    __syncthreads();

    // One timestep. bA holds kt11, bB holds kt12 on entry; on exit bB holds
    // next-step kt11, bA next-step kt12 (roles swap -> 2-step unrolled loop).
    auto body = [&](int t, int pp, f16x8(&bA)[4], f16x8(&bB)[4]) {
        // opaque per-iter handles: defeat LICM on loop-invariant weight loads
        uintptr_t whu = (uintptr_t)Whh_p;
        asm volatile("" : "+s"(whu));
        const f16* wbase = (const f16*)whu + ((size_t)ntg0 * 64 + lane) * 8;
        u32 zo = 0;
        asm volatile("" : "+v"(zo));
        const f16x8* wlds = (const f16x8*)whh_lds + zo;

        // issue this step's xproj fragment loads (consumed pre-tanh)
        f32x4 xr32[4];
        f16x4 xr16[4];
        if constexpr (XP == 1) {
            const float* xq = xpf + (size_t)t * XSTRIDE;
#pragma unroll
            for (int nt = 0; nt < 4; nt++) xr32[nt] = *(const f32x4*)(xq + (size_t)nt * 256);
        } else if constexpr (XP == 2) {
            const f16* xq = xph + (size_t)t * XSTRIDE;
#pragma unroll
            for (int nt = 0; nt < 4; nt++) xr16[nt] = *(const f16x4*)(xq + (size_t)nt * 256);
        }

        f32x4 acc[4];
        if constexpr (XP == 0) {
#pragma unroll
            for (int nt = 0; nt < 4; nt++)
                acc[nt] = (f32x4){bh4[nt], bh4[nt], bh4[nt], bh4[nt]};
        } else {
#pragma unroll
            for (int nt = 0; nt < 4; nt++) acc[nt] = (f32x4){0.f, 0.f, 0.f, 0.f};
        }

        const f16* hb = &hbuf[pp][0][0];

        if constexpr (XP == 0) {
            float4 xv;
            const bool havex = (t + 1 < T);
            if (havex)
                xv = *(const float4*)&x[((size_t)(b0 + xrow) * T + (t + 1)) * D + xd0];
            uintptr_t wxu = (uintptr_t)Whx_p;
            asm volatile("" : "+s"(wxu));
            const f16* wxs = (const f16*)wxu;
#pragma unroll
            for (int kt = 0; kt < D / 32; kt++) {
                f16x8 a = load_a(&xbuf[pp][0][0], LDX, kt, l15, l4);
                const f16* bt = wxs + (((size_t)kt * NTG + ntg0) * 64 + lane) * 8;
#pragma unroll
                for (int nt = 0; nt < 4; nt++) {
                    f16x8 b = *(const f16x8*)(bt + (size_t)nt * 512);
                    acc[nt] = MFMA(a, b, acc[nt], 0, 0, 0);
                }
            }
            if (havex) {
                f16x4 h4 = {(f16)xv.x, (f16)xv.y, (f16)xv.z, (f16)xv.w};
                *(f16x4*)&xbuf[pp ^ 1][xrow][xd0] = h4;
            }
        }

        // ---- h @ Whh: pinned kt0..7 | LDS kt8..10 | streamed kt11..15 ----
        auto LS = [&](int kt, f16x8(&bf)[4]) {
#pragma unroll
            for (int nt = 0; nt < 4; nt++)
                bf[nt] = *(const f16x8*)(wbase + ((size_t)kt * NTG + nt) * 512);
        };
        auto PK = [&](int kt) {
            f16x8 a = load_a(hb, LDH, kt, l15, l4);
#pragma unroll
            for (int nt = 0; nt < 4; nt++)
                acc[nt] = MFMA(a, wreg[kt][nt], acc[nt], 0, 0, 0);
        };
        auto CL = [&](int ktl) {
            f16x8 a = load_a(hb, LDH, PKT + ktl, l15, l4);
#pragma unroll
            for (int nt = 0; nt < 4; nt++)
                acc[nt] = MFMA(a, wlds[((size_t)ktl * NTG + ntg0 + nt) * 64 + lane],
                               acc[nt], 0, 0, 0);
        };
        auto CS = [&](int kt, f16x8(&bf)[4]) {
            f16x8 a = load_a(hb, LDH, kt, l15, l4);
#pragma unroll
            for (int nt = 0; nt < 4; nt++) acc[nt] = MFMA(a, bf[nt], acc[nt], 0, 0, 0);
        };

        // schedule: prefetched 11/12 consumed first; 13/14 issued with ~7-group
        // distance; next-step 11/12 issued last (hide under tanh+barrier).
        PK(0); CS(11, bA); LS(13, bA);
        PK(1); CS(12, bB); LS(14, bB);
        PK(2); CL(0);
        PK(3); CL(1);
        PK(4); CL(2);
        PK(5); CS(13, bA); LS(15, bA);
        PK(6); CS(14, bB); LS(11, bB);
        PK(7); CS(15, bA); LS(12, bA);

        // h_new = tanh(acc [+ xproj]); C/D layout: col=lane&15, row=4*(lane>>4)+r
#pragma unroll
        for (int nt = 0; nt < 4; nt++)
#pragma unroll
            for (int r = 0; r < 4; r++) {
                float v = acc[nt][r];
                if constexpr (XP == 1) v += xr32[nt][r];
                else if constexpr (XP == 2) v += (float)xr16[nt][r];
                float th = fast_tanh(v);
                hbuf[pp ^ 1][l4 * 4 + r][(ntg0 + nt) * 16 + l15] = (f16)th;
            }
        __syncthreads();
    };

    for (int t = 0; t < T; t += 2) {
        body(t, 0, sA, sB);      // ends: sB=kt11, sA=kt12
        body(t + 1, 1, sB, sA);  // ends: sA=kt11, sB=kt12
    }

    // out = h_T @ Wph + bp ; h_T in hbuf[0] (T even). Wave w owns cols [w*16,+16).
    {
        float bpv = bp[w * 16 + l15];
        f32x4 acc = {bpv, bpv, bpv, bpv};
#pragma unroll 4
        for (int kt = 0; kt < H / 32; kt++) {
            f16x8 a = load_a(&hbuf[0][0][0], LDH, kt, l15, l4);
            f16x8 b = *(const f16x8*)(Wph_p + (((size_t)kt * (C / 16) + w) * 64 + lane) * 8);
            acc = MFMA(a, b, acc, 0, 0, 0);
        }
#pragma unroll
        for (int r = 0; r < 4; r++)
            out[(size_t)(b0 + l4 * 4 + r) * C + w * 16 + l15] = acc[r];
    }
}

extern "C" void kernel_launch(void* const* d_in, const int* in_sizes, int n_in,
                              void* d_out, int out_size, void* d_ws, size_t ws_size,
                              hipStream_t stream) {
    const float* x   = (const float*)d_in[0];
    const float* Whx = (const float*)d_in[1];
    const float* Whh = (const float*)d_in[2];
    const float* Wph = (const float*)d_in[3];
    const float* bh  = (const float*)d_in[4];
    const float* bp  = (const float*)d_in[5];

    f16* wp = (f16*)d_ws; // 768 KB packed fp16 weights
    pack_w<<<dim3(128), 256, 0, stream>>>(Whx, D, H, wp);
    pack_w<<<dim3(512), 256, 0, stream>>>(Whh, H, H, wp + D * H);
    pack_w<<<dim3(128), 256, 0, stream>>>(Wph, H, C, wp + D * H + H * H);

    const size_t wbytes = (size_t)(D * H + H * H + H * C) * sizeof(f16); // 768 KB
    const size_t xpel   = (size_t)T * 16 * NTG * 256;                    // 67.1M elems

    if (ws_size >= wbytes + xpel * sizeof(float)) {        // 257 MB: f32 xproj
        float* xpb = (float*)((char*)d_ws + wbytes);
        xproj_k<float><<<dim3(16, T / 16), TPB, 0, stream>>>(x, wp, bh, xpb);
        rnn_main<1><<<dim3(Bsz / ROWS), TPB, 0, stream>>>(x, wp, xpb, bh, bp,
                                                          (float*)d_out);
    } else if (ws_size >= wbytes + xpel * sizeof(f16)) {   // 129 MB: f16 xproj
        f16* xpb = (f16*)((char*)d_ws + wbytes);
        xproj_k<f16><<<dim3(16, T / 16), TPB, 0, stream>>>(x, wp, bh, xpb);
        rnn_main<2><<<dim3(Bsz / ROWS), TPB, 0, stream>>>(x, wp, xpb, bh, bp,
                                                          (float*)d_out);
    } else {                                               // fallback: in-loop Whx
        rnn_main<0><<<dim3(Bsz / ROWS), TPB, 0, stream>>>(x, wp, nullptr, bh, bp,
                                                          (float*)d_out);
    }
}

// Round 5
// 1407.971 us; speedup vs baseline: 4.2730x; 1.1736x over previous
//
#include <hip/hip_runtime.h>
#include <type_traits>

typedef _Float16 f16;
typedef f16 f16x4 __attribute__((ext_vector_type(4)));
typedef f16 f16x8 __attribute__((ext_vector_type(8)));
typedef float f32x4 __attribute__((ext_vector_type(4)));
typedef unsigned int u32;

#define MFMA __builtin_amdgcn_mfma_f32_16x16x32_f16

constexpr int Bsz = 256, T = 512, D = 128, H = 512, C = 128;
constexpr int ROWS = 16;          // batch rows per block (MFMA M)
constexpr int TPB  = 512;         // 8 waves
constexpr int LDH  = H + 8;       // stride 520 f16 = 260 dwords ≡ 4 mod 32: b128 bank-uniform
constexpr int LDX  = D + 8;
constexpr int NTG  = H / 16;      // 32 n-tiles over H
constexpr int PKT  = 8;           // Whh k-tiles pinned in regs (kt 0..7)
constexpr int KTL  = 3;           // Whh k-tiles in LDS (kt 8..10); kt 11..15 streamed
constexpr size_t XSTRIDE = (size_t)16 * NTG * 256;  // xproj elems per timestep

// Pack fp32 [K][N] row-major -> fp16 MFMA-fragment order.
// k-slot map (BIJECTION, must match A-side load_a): k = kt*32 + 8*(lane>>4) + e.
__global__ void pack_w(const float* __restrict__ W, int K, int N, f16* __restrict__ out) {
    int total = K * N;
    int NT = N / 16;
    for (int idx = blockIdx.x * blockDim.x + threadIdx.x; idx < total;
         idx += gridDim.x * blockDim.x) {
        int e    = idx & 7;
        int lane = (idx >> 3) & 63;
        int tile = idx >> 9;
        int kt = tile / NT, nt = tile % NT;
        int k = kt * 32 + 8 * (lane >> 4) + e;   // contiguous k-map
        int n = nt * 16 + (lane & 15);
        out[idx] = (f16)W[(size_t)k * N + n];
    }
}

// A-fragment: row = lane&15, k = kt*32 + 8*(lane>>4) + {0..7} -> one b128 read.
__device__ __forceinline__ f16x8 load_a(const f16* base, int ld, int kt, int l15, int l4) {
    return *(const f16x8*)(base + l15 * ld + kt * 32 + 8 * l4);
}

// tanh(v) = 1 - 2/(e^{2v}+1); exp->inf => rcp->0 => +/-1 (no clamp needed).
__device__ __forceinline__ float fast_tanh(float v) {
    float e = __expf(2.f * v);
    return 1.f - __fdividef(2.f, e + 1.f);
}

// xproj = x_t @ Whx + bh in MFMA C-fragment order (f32 or f16). Runs on all CUs.
template <typename OT>
__global__ __launch_bounds__(TPB, 2) void xproj_k(
    const float* __restrict__ x, const f16* __restrict__ wpack,
    const float* __restrict__ bh, OT* __restrict__ xp) {
    const f16* Whx_p = wpack;
    __shared__ __align__(16) f16 xb[2][ROWS][LDX];
    const int tid = threadIdx.x, lane = tid & 63, w = tid >> 6;
    const int l15 = lane & 15, l4 = lane >> 4;
    const int bt = blockIdx.x;       // 0..15
    const int t0 = blockIdx.y * 16;  // chunks of 16 timesteps
    const int b0 = bt * ROWS;
    const int xrow = tid >> 5, xd0 = (tid & 31) * 4;
    const int ntg0 = w * 4;

    float bh4[4];
#pragma unroll
    for (int nt = 0; nt < 4; nt++) bh4[nt] = bh[(ntg0 + nt) * 16 + l15];
    {
        float4 v = *(const float4*)&x[((size_t)(b0 + xrow) * T + t0) * D + xd0];
        f16x4 h4 = {(f16)v.x, (f16)v.y, (f16)v.z, (f16)v.w};
        *(f16x4*)&xb[0][xrow][xd0] = h4;
    }
    __syncthreads();

    int p = 0;
    for (int tt = 0; tt < 16; tt++) {
        int t = t0 + tt;
        float4 xv;
        const bool havex = (tt + 1 < 16);
        if (havex)
            xv = *(const float4*)&x[((size_t)(b0 + xrow) * T + (t + 1)) * D + xd0];
        f32x4 acc[4];
#pragma unroll
        for (int nt = 0; nt < 4; nt++)
            acc[nt] = (f32x4){bh4[nt], bh4[nt], bh4[nt], bh4[nt]};
#pragma unroll
        for (int kt = 0; kt < D / 32; kt++) {
            f16x8 a = load_a(&xb[p][0][0], LDX, kt, l15, l4);
            const f16* btp = Whx_p + (((size_t)kt * NTG + ntg0) * 64 + lane) * 8;
#pragma unroll
            for (int nt = 0; nt < 4; nt++) {
                f16x8 b = *(const f16x8*)(btp + (size_t)nt * 512);
                acc[nt] = MFMA(a, b, acc[nt], 0, 0, 0);
            }
        }
        if (havex) {
            f16x4 h4 = {(f16)xv.x, (f16)xv.y, (f16)xv.z, (f16)xv.w};
            *(f16x4*)&xb[p ^ 1][xrow][xd0] = h4;
        }
        OT* op = xp + (((size_t)t * 16 + bt) * NTG + ntg0) * 256 + (size_t)lane * 4;
#pragma unroll
        for (int nt = 0; nt < 4; nt++) {
            if constexpr (std::is_same_v<OT, float>) {
                *(f32x4*)(op + (size_t)nt * 256) = acc[nt];
            } else {
                f16x4 v = {(f16)acc[nt][0], (f16)acc[nt][1], (f16)acc[nt][2],
                           (f16)acc[nt][3]};
                *(f16x4*)(op + (size_t)nt * 256) = v;
            }
        }
        __syncthreads();
        p ^= 1;
    }
}

// XP=1: f32 xproj. XP=2: f16 xproj. XP=0: in-loop Whx fallback (barrier-synced).
// XP!=0: no per-step barrier — producer/consumer LDS flags + 3-ring hbuf.
template <int XP>
__global__ __launch_bounds__(TPB, 2) void rnn_main(
    const float* __restrict__ x, const f16* __restrict__ wpack,
    const void* __restrict__ xproj, const float* __restrict__ bh,
    const float* __restrict__ bp, float* __restrict__ out) {
    const f16* Whx_p = wpack;
    const f16* Whh_p = wpack + D * H;
    const f16* Wph_p = wpack + D * H + H * H;

    __shared__ __align__(16) f16 hbuf[3][ROWS][LDH];           // 49.9 KB ring
    __shared__ __align__(16) f16 whh_lds[KTL * NTG * 64 * 8];  // 96 KB, kt 8..10
    __shared__ u32 pflag[8];  // pflag[v]=s: wave v's chunk of h_s readable
    __shared__ __align__(16) f16 xbuf[(XP == 0) ? 2 : 1][(XP == 0) ? ROWS : 1]
                                     [(XP == 0) ? LDX : 8];

    const int tid = threadIdx.x, lane = tid & 63, w = tid >> 6;
    const int l15 = lane & 15, l4 = lane >> 4;
    const int b0 = blockIdx.x * ROWS;
    const int xrow = tid >> 5, xd0 = (tid & 31) * 4;
    const int ntg0 = w * 4;

    // Pinned Whh kt 0..7 (128 regs, AGPR-resident).
    f16x8 wreg[PKT][4];
#pragma unroll
    for (int kt = 0; kt < PKT; kt++)
#pragma unroll
        for (int nt = 0; nt < 4; nt++)
            wreg[kt][nt] =
                *(const f16x8*)(Whh_p + (((size_t)kt * NTG + ntg0 + nt) * 64 + lane) * 8);

    // Stage Whh kt 8..10 into LDS.
    {
        const f16* src = Whh_p + (size_t)PKT * NTG * 512;
        for (int i = tid; i < KTL * NTG * 64; i += TPB)
            *(f16x8*)&whh_lds[(size_t)i * 8] = *(const f16x8*)(src + (size_t)i * 8);
    }
    for (int i = tid; i < ROWS * LDH; i += TPB) (&hbuf[0][0][0])[i] = (f16)0.f;
    if (tid < 8) pflag[tid] = 0u;  // h_0 ready

    float bh4[4];
    const float* xpf = nullptr;
    const f16* xph = nullptr;
    if constexpr (XP == 1) {
        xpf = (const float*)xproj + (((size_t)blockIdx.x * NTG + ntg0) * 64 + lane) * 4;
    } else if constexpr (XP == 2) {
        xph = (const f16*)xproj + (((size_t)blockIdx.x * NTG + ntg0) * 64 + lane) * 4;
    } else {
#pragma unroll
        for (int nt = 0; nt < 4; nt++) bh4[nt] = bh[(ntg0 + nt) * 16 + l15];
        float4 v = *(const float4*)&x[((size_t)(b0 + xrow) * T + 0) * D + xd0];
        f16x4 h4 = {(f16)v.x, (f16)v.y, (f16)v.z, (f16)v.w};
        *(f16x4*)&xbuf[0][xrow][xd0] = h4;
    }

    // Prologue: preload streamed kt 11 -> sA, kt 12 -> sB.
    f16x8 sA[4], sB[4];
    {
        const f16* wb0 = Whh_p + ((size_t)ntg0 * 64 + lane) * 8;
#pragma unroll
        for (int nt = 0; nt < 4; nt++)
            sA[nt] = *(const f16x8*)(wb0 + ((size_t)11 * NTG + nt) * 512);
#pragma unroll
        for (int nt = 0; nt < 4; nt++)
            sB[nt] = *(const f16x8*)(wb0 + ((size_t)12 * NTG + nt) * 512);
    }
    __syncthreads();  // one-time: init + pflag visible

    // Acquire-spin on producer v's step-tgt publish (no-op for own tiles).
    auto spin = [&](int v, u32 tgt) {
        if constexpr (XP != 0) {
            if (v != w)
                while (__hip_atomic_load(&pflag[v], __ATOMIC_ACQUIRE,
                                         __HIP_MEMORY_SCOPE_WORKGROUP) < tgt) {
                }
        }
    };

    // One timestep: reads h_t from hb, writes h_{t+1} to hw.
    // Entry: bA=kt11, bB=kt12 prefetched. Exit: bA=kt12', bB=kt11' (roles swap).
    auto body = [&](u32 t, const f16* hb, f16* hw, f16x8(&bA)[4], f16x8(&bB)[4],
                    int pp) {
        uintptr_t whu = (uintptr_t)Whh_p;
        asm volatile("" : "+s"(whu));
        const f16* wbase = (const f16*)whu + ((size_t)ntg0 * 64 + lane) * 8;
        u32 zo = 0;
        asm volatile("" : "+v"(zo));
        const f16x8* wlds = (const f16x8*)whh_lds + zo;

        // issue this step's xproj fragment loads (consumed pre-tanh)
        f32x4 xr32[4];
        f16x4 xr16[4];
        if constexpr (XP == 1) {
            const float* xq = xpf + (size_t)t * XSTRIDE;
#pragma unroll
            for (int nt = 0; nt < 4; nt++) xr32[nt] = *(const f32x4*)(xq + (size_t)nt * 256);
        } else if constexpr (XP == 2) {
            const f16* xq = xph + (size_t)t * XSTRIDE;
#pragma unroll
            for (int nt = 0; nt < 4; nt++) xr16[nt] = *(const f16x4*)(xq + (size_t)nt * 256);
        }

        f32x4 acc[4];
        if constexpr (XP == 0) {
#pragma unroll
            for (int nt = 0; nt < 4; nt++)
                acc[nt] = (f32x4){bh4[nt], bh4[nt], bh4[nt], bh4[nt]};
        } else {
#pragma unroll
            for (int nt = 0; nt < 4; nt++) acc[nt] = (f32x4){0.f, 0.f, 0.f, 0.f};
        }

        if constexpr (XP == 0) {
            float4 xv;
            const bool havex = (t + 1 < T);
            if (havex)
                xv = *(const float4*)&x[((size_t)(b0 + xrow) * T + (t + 1)) * D + xd0];
            uintptr_t wxu = (uintptr_t)Whx_p;
            asm volatile("" : "+s"(wxu));
            const f16* wxs = (const f16*)wxu;
#pragma unroll
            for (int kt = 0; kt < D / 32; kt++) {
                f16x8 a = load_a(&xbuf[pp][0][0], LDX, kt, l15, l4);
                const f16* bt = wxs + (((size_t)kt * NTG + ntg0) * 64 + lane) * 8;
#pragma unroll
                for (int nt = 0; nt < 4; nt++) {
                    f16x8 b = *(const f16x8*)(bt + (size_t)nt * 512);
                    acc[nt] = MFMA(a, b, acc[nt], 0, 0, 0);
                }
            }
            if (havex) {
                f16x4 h4 = {(f16)xv.x, (f16)xv.y, (f16)xv.z, (f16)xv.w};
                *(f16x4*)&xbuf[pp ^ 1][xrow][xd0] = h4;
            }
        }

        // ---- h @ Whh: pinned kt0..7 | LDS kt8..10 | streamed kt11..15 ----
        // A-fragment kt needs h-cols [kt*32,+32) = producer wave kt>>1.
        auto LS = [&](int kt, f16x8(&bf)[4]) {
#pragma unroll
            for (int nt = 0; nt < 4; nt++)
                bf[nt] = *(const f16x8*)(wbase + ((size_t)kt * NTG + nt) * 512);
        };
        auto PK = [&](int kt) {
            f16x8 a = load_a(hb, LDH, kt, l15, l4);
#pragma unroll
            for (int nt = 0; nt < 4; nt++)
                acc[nt] = MFMA(a, wreg[kt][nt], acc[nt], 0, 0, 0);
        };
        auto CL = [&](int ktl) {
            f16x8 a = load_a(hb, LDH, PKT + ktl, l15, l4);
#pragma unroll
            for (int nt = 0; nt < 4; nt++)
                acc[nt] = MFMA(a, wlds[((size_t)ktl * NTG + ntg0 + nt) * 64 + lane],
                               acc[nt], 0, 0, 0);
        };
        auto CS = [&](int kt, f16x8(&bf)[4]) {
            f16x8 a = load_a(hb, LDH, kt, l15, l4);
#pragma unroll
            for (int nt = 0; nt < 4; nt++) acc[nt] = MFMA(a, bf[nt], acc[nt], 0, 0, 0);
        };

        // fixed kt order: streams interleaved (>=5-group load-use distance);
        // spin on each producer before its first A-use.
        spin(0, t); PK(0); PK(1);
        spin(5, t); CS(11, bA); LS(13, bA);
        spin(1, t); PK(2); PK(3);
        spin(6, t); CS(12, bB); LS(14, bB);
        spin(2, t); PK(4); PK(5);
                    CS(13, bA); LS(15, bA);
        spin(3, t); PK(6); PK(7);
                    CS(14, bB); LS(11, bB);   // next-step kt11
        spin(4, t); CL(0); CL(1);
                    CS(15, bA); LS(12, bA);   // next-step kt12
                    CL(2);

        // h_new = tanh(acc [+ xproj]); C/D layout: col=lane&15, row=4*(lane>>4)+r
#pragma unroll
        for (int nt = 0; nt < 4; nt++)
#pragma unroll
            for (int r = 0; r < 4; r++) {
                float v = acc[nt][r];
                if constexpr (XP == 1) v += xr32[nt][r];
                else if constexpr (XP == 2) v += (float)xr16[nt][r];
                float th = fast_tanh(v);
                hw[(l4 * 4 + r) * LDH + (ntg0 + nt) * 16 + l15] = (f16)th;
            }
        if constexpr (XP != 0) {
            if (lane == 0)
                __hip_atomic_store(&pflag[w], t + 1, __ATOMIC_RELEASE,
                                   __HIP_MEMORY_SCOPE_WORKGROUP);
        } else {
            __syncthreads();
        }
    };

    f16* r0 = &hbuf[0][0][0];
    f16* r1 = &hbuf[1][0][0];
    f16* r2 = &hbuf[2][0][0];
    for (u32 t = 0; t < T; t += 2) {
        body(t,     r0, r1, sA, sB, 0);  // exit: sB=kt11', sA=kt12'
        body(t + 1, r1, r2, sB, sA, 1);  // exit: sA=kt11'', sB=kt12''
        f16* n0 = r2; f16* n1 = r0; f16* n2 = r1;  // 3-ring rotate by 2
        r0 = n0; r1 = n1; r2 = n2;
    }
    // after loop h_T sits in r0 (T even: last write was to old r2 == new r0)

    // wait for all waves' h_T publish, then out = h_T @ Wph + bp
    if constexpr (XP != 0) {
#pragma unroll
        for (int v = 0; v < 8; v++) spin(v, (u32)T);
    }
    {
        float bpv = bp[w * 16 + l15];
        f32x4 acc = {bpv, bpv, bpv, bpv};
#pragma unroll 4
        for (int kt = 0; kt < H / 32; kt++) {
            f16x8 a = load_a(r0, LDH, kt, l15, l4);
            f16x8 b = *(const f16x8*)(Wph_p + (((size_t)kt * (C / 16) + w) * 64 + lane) * 8);
            acc = MFMA(a, b, acc, 0, 0, 0);
        }
#pragma unroll
        for (int r = 0; r < 4; r++)
            out[(size_t)(b0 + l4 * 4 + r) * C + w * 16 + l15] = acc[r];
    }
}

extern "C" void kernel_launch(void* const* d_in, const int* in_sizes, int n_in,
                              void* d_out, int out_size, void* d_ws, size_t ws_size,
                              hipStream_t stream) {
    const float* x   = (const float*)d_in[0];
    const float* Whx = (const float*)d_in[1];
    const float* Whh = (const float*)d_in[2];
    const float* Wph = (const float*)d_in[3];
    const float* bh  = (const float*)d_in[4];
    const float* bp  = (const float*)d_in[5];

    f16* wp = (f16*)d_ws; // 768 KB packed fp16 weights
    pack_w<<<dim3(128), 256, 0, stream>>>(Whx, D, H, wp);
    pack_w<<<dim3(512), 256, 0, stream>>>(Whh, H, H, wp + D * H);
    pack_w<<<dim3(128), 256, 0, stream>>>(Wph, H, C, wp + D * H + H * H);

    const size_t wbytes = (size_t)(D * H + H * H + H * C) * sizeof(f16); // 768 KB
    const size_t xpel   = (size_t)T * 16 * NTG * 256;                    // 67.1M elems

    if (ws_size >= wbytes + xpel * sizeof(float)) {        // 257 MB: f32 xproj
        float* xpb = (float*)((char*)d_ws + wbytes);
        xproj_k<float><<<dim3(16, T / 16), TPB, 0, stream>>>(x, wp, bh, xpb);
        rnn_main<1><<<dim3(Bsz / ROWS), TPB, 0, stream>>>(x, wp, xpb, bh, bp,
                                                          (float*)d_out);
    } else if (ws_size >= wbytes + xpel * sizeof(f16)) {   // 129 MB: f16 xproj
        f16* xpb = (f16*)((char*)d_ws + wbytes);
        xproj_k<f16><<<dim3(16, T / 16), TPB, 0, stream>>>(x, wp, bh, xpb);
        rnn_main<2><<<dim3(Bsz / ROWS), TPB, 0, stream>>>(x, wp, xpb, bh, bp,
                                                          (float*)d_out);
    } else {                                               // fallback: in-loop Whx
        rnn_main<0><<<dim3(Bsz / ROWS), TPB, 0, stream>>>(x, wp, nullptr, bh, bp,
                                                          (float*)d_out);
    }
}